// Round 11
// baseline (368.773 us; speedup 1.0000x reference)
//
#include <hip/hip_runtime.h>

// RGCN: fused padx+chunk-hist -> colscan -> LDS-staged grouping (atomic-free)
// -> per-bucket counting sort WITH FUSED LAYER-1 (sortb emits dst-sorted
// records w/ packed cnt AND computes h1 per dst from its LDS state) ->
// 16-lane-per-dst register gathers for L2/L3.
// R10 postmortem: neutral — pipeline latency-dominated, ~310us spread across
// sortb + 3 layer passes. R11 deletes the l1 pass entirely (sortb already
// holds stage order, counts, segment bases in LDS).

#define NREL   90
#define BSH    7
#define BNODES 128       // nodes per bucket
#define NBINS  1024      // padded bucket count (N <= 131072)
#define GCH    6912      // edges per grouping chunk
#define STAGE  9216      // sortb bucket capacity; mean 8192, sigma ~90
#define LPD    16        // dsts per block in layer kernels (16 lanes each)

__device__ __forceinline__ float frelu(float v) { return v > 0.0f ? v : 0.0f; }

// ---------- K1: fused pad-x + per-chunk bucket histogram ----------
__launch_bounds__(512)
__global__ void padhist_k(const float* __restrict__ x, float4* __restrict__ x4, int N,
                          int gNp, const int* __restrict__ dst, int* __restrict__ bhist,
                          int* __restrict__ chist, int E) {
    int tid = threadIdx.x;
    if (blockIdx.x < gNp) {           // pad role
        int i = blockIdx.x * 512 + tid;
        if (i < N) x4[i] = make_float4(x[3 * i], x[3 * i + 1], x[3 * i + 2], 0.0f);
        return;
    }
    __shared__ int h[NBINS];
    for (int i = tid; i < NBINS; i += 512) h[i] = 0;
    __syncthreads();
    int chunk = blockIdx.x - gNp;
    int e0 = chunk * GCH;
    int e1 = min(e0 + GCH, E);
    int e = e0 + tid;
    for (; e + 1536 < e1; e += 2048) {
        int d0 = dst[e], d1 = dst[e + 512], d2 = dst[e + 1024], d3 = dst[e + 1536];
        atomicAdd(&h[d0 >> BSH], 1); atomicAdd(&h[d1 >> BSH], 1);
        atomicAdd(&h[d2 >> BSH], 1); atomicAdd(&h[d3 >> BSH], 1);
    }
    for (; e < e1; e += 512) atomicAdd(&h[dst[e] >> BSH], 1);
    __syncthreads();
    int base = chunk * NBINS;
    for (int i = tid; i < NBINS; i += 512) {
        int c = h[i];
        chist[base + i] = c;
        if (c) atomicAdd(&bhist[i], c);
    }
}

// ---------- K2: per-bucket column scan over chunks ----------
__global__ void colscan_k(const int* __restrict__ bhist, int* __restrict__ bbase,
                          const int* __restrict__ chist, int* __restrict__ gbase,
                          int nchunks) {
    int b = blockIdx.x;          // one wave per bucket column
    int lane = threadIdx.x;      // 64
    int part = 0;
    int b0 = lane * 16;
#pragma unroll
    for (int k = 0; k < 16; k++) {
        int bin = b0 + k;
        int v = bhist[bin];
        if (bin < b) part += v;
    }
#pragma unroll
    for (int off = 32; off > 0; off >>= 1) part += __shfl_down(part, off);
    int run = __shfl(part, 0);
    if (lane == 0) bbase[b] = run;
    for (int c0 = 0; c0 < nchunks; c0 += 64) {
        int c = c0 + lane;
        int v = (c < nchunks) ? chist[(size_t)c * NBINS + b] : 0;
        int inc = v;
#pragma unroll
        for (int off = 1; off < 64; off <<= 1) {
            int u = __shfl_up(inc, off);
            if (lane >= off) inc += u;
        }
        if (c < nchunks) gbase[(size_t)c * NBINS + b] = run + inc - v;
        run += __shfl(inc, 63);
    }
}

// ---------- K3: LDS-staged grouping (atomic-free vs global) ----------
// grouped record = src | rel<<17 | dstLocal<<24
__launch_bounds__(512)
__global__ void group_k(const int* __restrict__ src, const int* __restrict__ dst,
                        const int* __restrict__ et, const int* __restrict__ chist,
                        const int* __restrict__ gbase, unsigned* __restrict__ edges, int E) {
    __shared__ int s_cur[NBINS];
    __shared__ int s_gb2[NBINS];
    __shared__ unsigned s_pack[GCH];
    __shared__ unsigned short s_bkt[GCH];
    int tid = threadIdx.x;
    int chunk = blockIdx.x;
    int e0 = chunk * GCH;
    int cnt = min(GCH, E - e0);
    const int* crow = &chist[(size_t)chunk * NBINS];
    const int* grow = &gbase[(size_t)chunk * NBINS];
    if (tid < 64) {
        int loc[16];
        int s = 0;
        int b0 = tid * 16;
#pragma unroll
        for (int k = 0; k < 16; k++) { loc[k] = crow[b0 + k]; s += loc[k]; }
        int inc = s;
#pragma unroll
        for (int off = 1; off < 64; off <<= 1) {
            int u = __shfl_up(inc, off);
            if (tid >= off) inc += u;
        }
        int run = inc - s;
#pragma unroll
        for (int k = 0; k < 16; k++) { s_cur[b0 + k] = run; run += loc[k]; }
    }
    __syncthreads();
    for (int i = tid; i < NBINS; i += 512) s_gb2[i] = grow[i] - s_cur[i];
    __syncthreads();
    int q = tid;
    for (; q + 1536 < cnt; q += 2048) {
#pragma unroll
        for (int k = 0; k < 4; k++) {
            int e = e0 + q + k * 512;
            int d = dst[e];
            int b = d >> BSH;
            int p = atomicAdd(&s_cur[b], 1);
            if (p < GCH) {
                s_pack[p] = (unsigned)src[e] | ((unsigned)et[e] << 17) |
                            ((unsigned)(d & (BNODES - 1)) << 24);
                s_bkt[p] = (unsigned short)b;
            }
        }
    }
    for (; q < cnt; q += 512) {
        int e = e0 + q;
        int d = dst[e];
        int b = d >> BSH;
        int p = atomicAdd(&s_cur[b], 1);
        if (p < GCH) {
            s_pack[p] = (unsigned)src[e] | ((unsigned)et[e] << 17) |
                        ((unsigned)(d & (BNODES - 1)) << 24);
            s_bkt[p] = (unsigned short)b;
        }
    }
    __syncthreads();
    q = tid;
    for (; q + 1536 < cnt; q += 2048) {
#pragma unroll
        for (int k = 0; k < 4; k++) {
            int i = q + k * 512;
            edges[s_gb2[s_bkt[i]] + i] = s_pack[i];
        }
    }
    for (; q < cnt; q += 512) edges[s_gb2[s_bkt[q]] + q] = s_pack[q];
}

// ---------- K4: counting sort + FUSED LAYER 1 ----------
// emits edges2 record = src | rel<<17 | cnt<<24, rowptr, and h1p = L1 output
__launch_bounds__(512)
__global__ void sortb_l1_k(const int* __restrict__ bbase, const unsigned* __restrict__ edges,
                           unsigned* __restrict__ edges2, int* __restrict__ rowptr,
                           const float4* __restrict__ x4, const float* __restrict__ W,
                           const float* __restrict__ root, const float* __restrict__ bias,
                           float4* __restrict__ h1p, int N, int E) {
    __shared__ unsigned short stage16[STAGE];  // 18432 B
    __shared__ unsigned hist16[BNODES * 45];   // 23040 B
    __shared__ int hh[BNODES], cur[BNODES], base_[BNODES];
    __shared__ float4 w4[NREL * 2];            // 2880 B -> ~46 KB total
    int tid = threadIdx.x, b = blockIdx.x;
    for (int i = tid; i < BNODES * 45; i += 512) hist16[i] = 0u;
    for (int i = tid; i < NREL * 2; i += 512) {
        int r = i >> 1;
        w4[i] = (i & 1) ? make_float4(W[r * 6 + 4], W[r * 6 + 5], 0.f, 0.f)
                        : make_float4(W[r * 6], W[r * 6 + 1], W[r * 6 + 2], W[r * 6 + 3]);
    }
    __syncthreads();
    int e0 = bbase[b];
    int e1 = (b + 1 < NBINS) ? bbase[b + 1] : E;
    int cnt = e1 - e0;
    // phase A: (dL, rel) histogram (x4 unrolled)
    int e = e0 + tid;
    for (; e + 1536 < e1; e += 2048) {
#pragma unroll
        for (int k = 0; k < 4; k++) {
            unsigned p = edges[e + k * 512];
            unsigned idx = (p >> 24) * 90u + ((p >> 17) & 127u);
            atomicAdd(&hist16[idx >> 1], 1u << ((idx & 1) << 4));
        }
    }
    for (; e < e1; e += 512) {
        unsigned p = edges[e];
        unsigned idx = (p >> 24) * 90u + ((p >> 17) & 127u);
        atomicAdd(&hist16[idx >> 1], 1u << ((idx & 1) << 4));
    }
    __syncthreads();
    if (tid < BNODES) {   // per-dst totals
        unsigned s = 0;
        for (int k = 0; k < 45; k++) {
            unsigned wv = hist16[tid * 45 + k];
            s += (wv & 0xFFFFu) + (wv >> 16);
        }
        hh[tid] = (int)s;
    }
    __syncthreads();
    if (tid < 64) {       // exclusive scan of 128 bins, 2/lane
        int c0 = hh[2 * tid], c1 = hh[2 * tid + 1];
        int s = c0 + c1;
        int inc = s;
#pragma unroll
        for (int off = 1; off < 64; off <<= 1) {
            int u = __shfl_up(inc, off);
            if (tid >= off) inc += u;
        }
        int run = inc - s;
        base_[2 * tid] = run;          cur[2 * tid] = run;
        base_[2 * tid + 1] = run + c0; cur[2 * tid + 1] = run + c0;
    }
    __syncthreads();
    if (tid < BNODES) {
        int d = (b << BSH) + tid;
        if (d <= N) rowptr[d] = e0 + base_[tid];
    }
    // phase B: place local indices into dst-sorted stage (x4 unrolled)
    int i = tid;
    for (; i + 1536 < cnt; i += 2048) {
#pragma unroll
        for (int k = 0; k < 4; k++) {
            int ii = i + k * 512;
            unsigned p = edges[e0 + ii];
            int pos = atomicAdd(&cur[p >> 24], 1);
            if (pos < STAGE) stage16[pos] = (unsigned short)ii;
        }
    }
    for (; i < cnt; i += 512) {
        unsigned p = edges[e0 + i];
        int pos = atomicAdd(&cur[p >> 24], 1);
        if (pos < STAGE) stage16[pos] = (unsigned short)i;
    }
    __syncthreads();
    // phase C (fused L1): 32 groups of 16 lanes; each group handles 4 dsts.
    // Per dst: walk its contiguous stage segment, emit edges2 (+cnt packed),
    // accumulate L1 message in registers, 16-lane reduce, lane0 node op.
    int grp = tid >> 4, l16 = tid & 15;
#pragma unroll
    for (int rd = 0; rd < 4; rd++) {
        int dL = grp + rd * 32;
        int segb = base_[dL];
        int sege = segb + hh[dL];
        if (sege > cnt) sege = cnt;      // safety (never triggers if STAGE holds)
        float a0 = 0, a1 = 0, a2 = 0, a3 = 0, a4 = 0, a5 = 0;
        for (int q = segb + l16; q < sege; q += 16) {
            int ii = stage16[q];
            unsigned p = edges[e0 + ii];          // L1/L2-resident 32KB slice
            unsigned rel = (p >> 17) & 127u;
            unsigned idx = dL * 90u + rel;
            unsigned c = (hist16[idx >> 1] >> ((idx & 1) << 4)) & 0xFFu;
            edges2[e0 + q] = (p & 0x00FFFFFFu) | (c << 24);
            float r = __builtin_amdgcn_rcpf((float)c);
            float4 xv = x4[p & 0x1FFFFu];
            unsigned rel2 = rel * 2u;
            float4 wa = w4[rel2], wb = w4[rel2 + 1];
            float x0 = xv.x * r, x1 = xv.y * r, x2 = xv.z * r;
            a0 += x0 * wa.x; a1 += x0 * wa.y;
            a2 += x1 * wa.z; a3 += x1 * wa.w;
            a4 += x2 * wb.x; a5 += x2 * wb.y;
        }
#pragma unroll
        for (int off = 8; off > 0; off >>= 1) {
            a0 += __shfl_down(a0, off); a1 += __shfl_down(a1, off); a2 += __shfl_down(a2, off);
            a3 += __shfl_down(a3, off); a4 += __shfl_down(a4, off); a5 += __shfl_down(a5, off);
        }
        if (l16 == 0) {
            int d = (b << BSH) + dL;
            if (d < N) {
                float4 xv = x4[d];
                float o[6] = {a0, a1, a2, a3, a4, a5};
#pragma unroll
                for (int j = 0; j < 6; j++)
                    o[j] = frelu(o[j] + xv.x * root[j] + xv.y * root[6 + j] +
                                 xv.z * root[12 + j] + bias[j]);
                h1p[d * 2]     = make_float4(o[0], o[1], o[2], o[3]);
                h1p[d * 2 + 1] = make_float4(o[4], o[5], 0.0f, 0.0f);
            }
        }
    }
}

// ---------- L2: 16 lanes per dst, sum aggr, fused node ----------
__launch_bounds__(256)
__global__ void l2_g(const int* __restrict__ rowptr, const unsigned* __restrict__ sorted,
                     const float4* __restrict__ h1p, const float* __restrict__ W,
                     const float* __restrict__ root, const float* __restrict__ bias,
                     float4* __restrict__ h2p, int N) {
    __shared__ float4 w4[NREL * 2];
    for (int i = threadIdx.x; i < NREL * 2; i += 256) {
        int r = i >> 1;
        w4[i] = (i & 1) ? make_float4(W[r * 6 + 4], W[r * 6 + 5], 0.f, 0.f)
                        : make_float4(W[r * 6], W[r * 6 + 1], W[r * 6 + 2], W[r * 6 + 3]);
    }
    __syncthreads();
    int grp = threadIdx.x >> 4, l16 = threadIdx.x & 15;
    int d = blockIdx.x * LPD + grp;
    if (d >= N) return;
    int beg = rowptr[d], end = rowptr[d + 1];
    float a0 = 0, a1 = 0, a2 = 0;
    int i = beg + l16;
    for (; i + 48 < end; i += 64) {
        unsigned p[4];
        float4 ha[4], hb[4];
#pragma unroll
        for (int k = 0; k < 4; k++) p[k] = sorted[i + k * 16];
#pragma unroll
        for (int k = 0; k < 4; k++) {
            unsigned s = p[k] & 0x1FFFFu;
            ha[k] = h1p[2 * s]; hb[k] = h1p[2 * s + 1];
        }
#pragma unroll
        for (int k = 0; k < 4; k++) {
            unsigned rel2 = ((p[k] >> 17) & 127u) * 2u;
            float4 wa = w4[rel2], wb = w4[rel2 + 1];
            a0 += ha[k].x * wa.x + ha[k].y * wa.y;
            a1 += ha[k].z * wa.z + ha[k].w * wa.w;
            a2 += hb[k].x * wb.x + hb[k].y * wb.y;
        }
    }
    for (; i < end; i += 16) {
        unsigned p = sorted[i];
        unsigned s = p & 0x1FFFFu;
        float4 ha = h1p[2 * s], hb = h1p[2 * s + 1];
        unsigned rel2 = ((p >> 17) & 127u) * 2u;
        float4 wa = w4[rel2], wb = w4[rel2 + 1];
        a0 += ha.x * wa.x + ha.y * wa.y;
        a1 += ha.z * wa.z + ha.w * wa.w;
        a2 += hb.x * wb.x + hb.y * wb.y;
    }
#pragma unroll
    for (int off = 8; off > 0; off >>= 1) {
        a0 += __shfl_down(a0, off); a1 += __shfl_down(a1, off); a2 += __shfl_down(a2, off);
    }
    if (l16 == 0) {
        float4 ha = h1p[2 * d], hb = h1p[2 * d + 1];
        float hv[6] = {ha.x, ha.y, ha.z, ha.w, hb.x, hb.y};
        float o[3] = {a0, a1, a2};
#pragma unroll
        for (int j = 0; j < 3; j++) {
            float v = o[j] + bias[j];
#pragma unroll
            for (int k = 0; k < 6; k++) v += hv[k] * root[k * 3 + j];
            o[j] = frelu(v);
        }
        h2p[d] = make_float4(o[0], o[1], o[2], 0.0f);
    }
}

// ---------- L3: 16 lanes per dst, mean via packed cnt, fused node + pool ----------
__launch_bounds__(256)
__global__ void l3_g(const int* __restrict__ rowptr, const unsigned* __restrict__ sorted,
                     const float4* __restrict__ h2p, const float* __restrict__ W,
                     const float* __restrict__ root, const float* __restrict__ bias,
                     const int* __restrict__ batch, float* __restrict__ partials, int N) {
    __shared__ float4 w4[NREL * 2];
    __shared__ float redsm[LPD][8];
    for (int i = threadIdx.x; i < NREL * 2; i += 256) {
        int r = i >> 1;
        w4[i] = (i & 1) ? make_float4(W[r * 6 + 4], W[r * 6 + 5], 0.f, 0.f)
                        : make_float4(W[r * 6], W[r * 6 + 1], W[r * 6 + 2], W[r * 6 + 3]);
    }
    __syncthreads();
    int grp = threadIdx.x >> 4, l16 = threadIdx.x & 15;
    int d = blockIdx.x * LPD + grp;
    float a0 = 0, a1 = 0, a2 = 0, a3 = 0, a4 = 0, a5 = 0;
    if (d < N) {
        int beg = rowptr[d], end = rowptr[d + 1];
        int i = beg + l16;
        for (; i + 48 < end; i += 64) {
            unsigned p[4];
            float4 xv[4];
#pragma unroll
            for (int k = 0; k < 4; k++) p[k] = sorted[i + k * 16];
#pragma unroll
            for (int k = 0; k < 4; k++) xv[k] = h2p[p[k] & 0x1FFFFu];
#pragma unroll
            for (int k = 0; k < 4; k++) {
                float r = __builtin_amdgcn_rcpf((float)(p[k] >> 24));
                unsigned rel2 = ((p[k] >> 17) & 127u) * 2u;
                float4 wa = w4[rel2], wb = w4[rel2 + 1];
                float x0 = xv[k].x * r, x1 = xv[k].y * r, x2 = xv[k].z * r;
                a0 += x0 * wa.x; a1 += x0 * wa.y;
                a2 += x1 * wa.z; a3 += x1 * wa.w;
                a4 += x2 * wb.x; a5 += x2 * wb.y;
            }
        }
        for (; i < end; i += 16) {
            unsigned p = sorted[i];
            float r = __builtin_amdgcn_rcpf((float)(p >> 24));
            float4 xv = h2p[p & 0x1FFFFu];
            unsigned rel2 = ((p >> 17) & 127u) * 2u;
            float4 wa = w4[rel2], wb = w4[rel2 + 1];
            float x0 = xv.x * r, x1 = xv.y * r, x2 = xv.z * r;
            a0 += x0 * wa.x; a1 += x0 * wa.y;
            a2 += x1 * wa.z; a3 += x1 * wa.w;
            a4 += x2 * wb.x; a5 += x2 * wb.y;
        }
    }
#pragma unroll
    for (int off = 8; off > 0; off >>= 1) {
        a0 += __shfl_down(a0, off); a1 += __shfl_down(a1, off); a2 += __shfl_down(a2, off);
        a3 += __shfl_down(a3, off); a4 += __shfl_down(a4, off); a5 += __shfl_down(a5, off);
    }
    if (l16 == 0) {
        float v[7] = {0, 0, 0, 0, 0, 0, 0};
        if (d < N && batch[d] == 0) {
            float4 xv = h2p[d];
            float o[6] = {a0, a1, a2, a3, a4, a5};
#pragma unroll
            for (int j = 0; j < 6; j++)
                v[j] = frelu(o[j] + xv.x * root[j] + xv.y * root[6 + j] +
                             xv.z * root[12 + j] + bias[j]);
            v[6] = 1.0f;
        }
#pragma unroll
        for (int k = 0; k < 7; k++) redsm[grp][k] = v[k];
    }
    __syncthreads();
    if (threadIdx.x < 7) {
        float t = 0;
#pragma unroll
        for (int g = 0; g < LPD; g++) t += redsm[g][threadIdx.x];
        partials[(size_t)blockIdx.x * 8 + threadIdx.x] = t;
    }
}

// ---------- finalize ----------
__global__ void pool_finalize(const float* __restrict__ partials, int nb,
                              float* __restrict__ out) {
    float v[7] = {0, 0, 0, 0, 0, 0, 0};
    for (int b = threadIdx.x; b < nb; b += blockDim.x) {
#pragma unroll
        for (int k = 0; k < 7; k++) v[k] += partials[(size_t)b * 8 + k];
    }
#pragma unroll
    for (int off = 32; off > 0; off >>= 1) {
#pragma unroll
        for (int k = 0; k < 7; k++) v[k] += __shfl_down(v[k], off);
    }
    __shared__ float sm[16][8];
    int wv = threadIdx.x >> 6, lane = threadIdx.x & 63;
    if (lane == 0) {
#pragma unroll
        for (int k = 0; k < 7; k++) sm[wv][k] = v[k];
    }
    __syncthreads();
    if (threadIdx.x == 0) {
        float t[7] = {0, 0, 0, 0, 0, 0, 0};
        int nw = blockDim.x >> 6;
        for (int q = 0; q < nw; q++) {
#pragma unroll
            for (int k = 0; k < 7; k++) t[k] += sm[q][k];
        }
        float c = t[6] < 1.0f ? 1.0f : t[6];
        float p[6], m = -1e30f;
#pragma unroll
        for (int j = 0; j < 6; j++) { p[j] = t[j] / c; m = fmaxf(m, p[j]); }
        float s = 0.0f;
#pragma unroll
        for (int j = 0; j < 6; j++) s += expf(p[j] - m);
        float lse = m + logf(s);
#pragma unroll
        for (int j = 0; j < 6; j++) out[j] = p[j] - lse;
    }
}

extern "C" void kernel_launch(void* const* d_in, const int* in_sizes, int n_in,
                              void* d_out, int out_size, void* d_ws, size_t ws_size,
                              hipStream_t stream) {
    const float* x     = (const float*)d_in[0];
    const int*   ei    = (const int*)d_in[1];
    const int*   batch = (const int*)d_in[2];
    const int*   etype = (const int*)d_in[3];
    const float* W1    = (const float*)d_in[4];
    const float* root1 = (const float*)d_in[5];
    const float* b1    = (const float*)d_in[6];
    const float* W2    = (const float*)d_in[7];
    const float* root2 = (const float*)d_in[8];
    const float* b2    = (const float*)d_in[9];
    const float* W3    = (const float*)d_in[10];
    const float* root3 = (const float*)d_in[11];
    const float* b3    = (const float*)d_in[12];

    const int N = in_sizes[0] / 3;
    const int E = in_sizes[1] / 2;
    const int* src = ei;
    const int* dst = ei + E;
    const int gG = (E + GCH - 1) / GCH;   // chunks

    char* ws = (char*)d_ws;
    size_t off = 0;
    auto alloc = [&](size_t bytes) -> void* {
        void* p = ws + off;
        off += (bytes + 255) & ~(size_t)255;
        return p;
    };
    int*      bhist   = (int*)     alloc(NBINS * sizeof(int));       // zeroed
    size_t zero_bytes = off;
    int*      bbase   = (int*)     alloc((NBINS + 1) * sizeof(int));
    int*      chist   = (int*)     alloc((size_t)gG * NBINS * sizeof(int));   // 3.8 MB
    int*      gbase   = (int*)     alloc((size_t)gG * NBINS * sizeof(int));   // 3.8 MB
    unsigned* edges   = (unsigned*)alloc((size_t)E * sizeof(unsigned));       // 25.6 MB
    unsigned* edges2  = (unsigned*)alloc((size_t)E * sizeof(unsigned));       // 25.6 MB
    int*      rowptr  = (int*)     alloc((size_t)(N + 1) * sizeof(int));
    float4*   x4      = (float4*)  alloc((size_t)N * sizeof(float4));
    float4*   h1p     = (float4*)  alloc((size_t)N * 2 * sizeof(float4));
    float4*   h2p     = (float4*)  alloc((size_t)N * sizeof(float4));
    const int NBUCK = (N + BNODES - 1) >> BSH;                                // 782
    const int gL    = (N + LPD - 1) / LPD;                                    // 6250
    float*    partials = (float*)  alloc((size_t)gL * 8 * sizeof(float));
    // total ~67 MB

    hipMemsetAsync(d_ws, 0, zero_bytes, stream);

    const int gNp = (N + 511) / 512;

    padhist_k<<<gNp + gG, 512, 0, stream>>>(x, x4, N, gNp, dst, bhist, chist, E);
    colscan_k<<<NBINS, 64, 0, stream>>>(bhist, bbase, chist, gbase, gG);
    group_k<<<gG, 512, 0, stream>>>(src, dst, etype, chist, gbase, edges, E);
    sortb_l1_k<<<NBUCK, 512, 0, stream>>>(bbase, edges, edges2, rowptr,
                                          x4, W1, root1, b1, h1p, N, E);

    l2_g<<<gL, 256, 0, stream>>>(rowptr, edges2, h1p, W2, root2, b2, h2p, N);
    l3_g<<<gL, 256, 0, stream>>>(rowptr, edges2, h2p, W3, root3, b3, batch, partials, N);
    pool_finalize<<<1, 1024, 0, stream>>>(partials, gL, (float*)d_out);
}

// Round 12
// 339.504 us; speedup vs baseline: 1.0862x; 1.0862x over previous
//
#include <hip/hip_runtime.h>

// RGCN: fused padx+chunk-hist -> colscan -> LDS-staged grouping (atomic-free)
// -> single-pass counting sort + FUSED LAYER-1 (records held in VGPRs across
// hist/place phases; stage holds full records; hist u8-packed) -> 16-lane-
// per-dst register gathers for L2/L3.
// R11 postmortem: sortb_l1 streamed edges from HBM 3x (77.6 MB FETCH). R12:
// one global read (regs across phases), phase C reads stage from LDS.

#define NREL   90
#define BSH    7
#define BNODES 128       // nodes per bucket
#define NBINS  1024      // padded bucket count (N <= 131072)
#define GCH    6912      // edges per grouping chunk
#define STAGE  9216      // sortb bucket capacity; mean 8192, sigma ~90 (+11s)
#define MAXK   18        // STAGE / 512 records per thread
#define LPD    16        // dsts per block in layer kernels (16 lanes each)

__device__ __forceinline__ float frelu(float v) { return v > 0.0f ? v : 0.0f; }

// ---------- K1: fused pad-x + per-chunk bucket histogram ----------
__launch_bounds__(512)
__global__ void padhist_k(const float* __restrict__ x, float4* __restrict__ x4, int N,
                          int gNp, const int* __restrict__ dst, int* __restrict__ bhist,
                          int* __restrict__ chist, int E) {
    int tid = threadIdx.x;
    if (blockIdx.x < gNp) {           // pad role
        int i = blockIdx.x * 512 + tid;
        if (i < N) x4[i] = make_float4(x[3 * i], x[3 * i + 1], x[3 * i + 2], 0.0f);
        return;
    }
    __shared__ int h[NBINS];
    for (int i = tid; i < NBINS; i += 512) h[i] = 0;
    __syncthreads();
    int chunk = blockIdx.x - gNp;
    int e0 = chunk * GCH;
    int e1 = min(e0 + GCH, E);
    int e = e0 + tid;
    for (; e + 1536 < e1; e += 2048) {
        int d0 = dst[e], d1 = dst[e + 512], d2 = dst[e + 1024], d3 = dst[e + 1536];
        atomicAdd(&h[d0 >> BSH], 1); atomicAdd(&h[d1 >> BSH], 1);
        atomicAdd(&h[d2 >> BSH], 1); atomicAdd(&h[d3 >> BSH], 1);
    }
    for (; e < e1; e += 512) atomicAdd(&h[dst[e] >> BSH], 1);
    __syncthreads();
    int base = chunk * NBINS;
    for (int i = tid; i < NBINS; i += 512) {
        int c = h[i];
        chist[base + i] = c;
        if (c) atomicAdd(&bhist[i], c);
    }
}

// ---------- K2: per-bucket column scan over chunks ----------
__global__ void colscan_k(const int* __restrict__ bhist, int* __restrict__ bbase,
                          const int* __restrict__ chist, int* __restrict__ gbase,
                          int nchunks) {
    int b = blockIdx.x;          // one wave per bucket column
    int lane = threadIdx.x;      // 64
    int part = 0;
    int b0 = lane * 16;
#pragma unroll
    for (int k = 0; k < 16; k++) {
        int bin = b0 + k;
        int v = bhist[bin];
        if (bin < b) part += v;
    }
#pragma unroll
    for (int off = 32; off > 0; off >>= 1) part += __shfl_down(part, off);
    int run = __shfl(part, 0);
    if (lane == 0) bbase[b] = run;
    for (int c0 = 0; c0 < nchunks; c0 += 64) {
        int c = c0 + lane;
        int v = (c < nchunks) ? chist[(size_t)c * NBINS + b] : 0;
        int inc = v;
#pragma unroll
        for (int off = 1; off < 64; off <<= 1) {
            int u = __shfl_up(inc, off);
            if (lane >= off) inc += u;
        }
        if (c < nchunks) gbase[(size_t)c * NBINS + b] = run + inc - v;
        run += __shfl(inc, 63);
    }
}

// ---------- K3: LDS-staged grouping (atomic-free vs global) ----------
// grouped record = src | rel<<17 | dstLocal<<24
__launch_bounds__(512)
__global__ void group_k(const int* __restrict__ src, const int* __restrict__ dst,
                        const int* __restrict__ et, const int* __restrict__ chist,
                        const int* __restrict__ gbase, unsigned* __restrict__ edges, int E) {
    __shared__ int s_cur[NBINS];
    __shared__ int s_gb2[NBINS];
    __shared__ unsigned s_pack[GCH];
    __shared__ unsigned short s_bkt[GCH];
    int tid = threadIdx.x;
    int chunk = blockIdx.x;
    int e0 = chunk * GCH;
    int cnt = min(GCH, E - e0);
    const int* crow = &chist[(size_t)chunk * NBINS];
    const int* grow = &gbase[(size_t)chunk * NBINS];
    if (tid < 64) {
        int loc[16];
        int s = 0;
        int b0 = tid * 16;
#pragma unroll
        for (int k = 0; k < 16; k++) { loc[k] = crow[b0 + k]; s += loc[k]; }
        int inc = s;
#pragma unroll
        for (int off = 1; off < 64; off <<= 1) {
            int u = __shfl_up(inc, off);
            if (tid >= off) inc += u;
        }
        int run = inc - s;
#pragma unroll
        for (int k = 0; k < 16; k++) { s_cur[b0 + k] = run; run += loc[k]; }
    }
    __syncthreads();
    for (int i = tid; i < NBINS; i += 512) s_gb2[i] = grow[i] - s_cur[i];
    __syncthreads();
    int q = tid;
    for (; q + 1536 < cnt; q += 2048) {
#pragma unroll
        for (int k = 0; k < 4; k++) {
            int e = e0 + q + k * 512;
            int d = dst[e];
            int b = d >> BSH;
            int p = atomicAdd(&s_cur[b], 1);
            if (p < GCH) {
                s_pack[p] = (unsigned)src[e] | ((unsigned)et[e] << 17) |
                            ((unsigned)(d & (BNODES - 1)) << 24);
                s_bkt[p] = (unsigned short)b;
            }
        }
    }
    for (; q < cnt; q += 512) {
        int e = e0 + q;
        int d = dst[e];
        int b = d >> BSH;
        int p = atomicAdd(&s_cur[b], 1);
        if (p < GCH) {
            s_pack[p] = (unsigned)src[e] | ((unsigned)et[e] << 17) |
                        ((unsigned)(d & (BNODES - 1)) << 24);
            s_bkt[p] = (unsigned short)b;
        }
    }
    __syncthreads();
    q = tid;
    for (; q + 1536 < cnt; q += 2048) {
#pragma unroll
        for (int k = 0; k < 4; k++) {
            int i = q + k * 512;
            edges[s_gb2[s_bkt[i]] + i] = s_pack[i];
        }
    }
    for (; q < cnt; q += 512) edges[s_gb2[s_bkt[q]] + q] = s_pack[q];
}

// ---------- K4: single-read counting sort + FUSED LAYER 1 ----------
// emits edges2 record = src | rel<<17 | cnt<<24, rowptr, h1p
__launch_bounds__(512)
__global__ void sortb_l1_k(const int* __restrict__ bbase, const unsigned* __restrict__ edges,
                           unsigned* __restrict__ edges2, int* __restrict__ rowptr,
                           const float4* __restrict__ x4, const float* __restrict__ W,
                           const float* __restrict__ root, const float* __restrict__ bias,
                           float4* __restrict__ h1p, int N, int E) {
    __shared__ unsigned stage32[STAGE];            // 36864 B, full records dst-sorted
    __shared__ unsigned hist8w[BNODES * 90 / 4];   // 11520 B, u8-packed (dL,rel) counts
    __shared__ int hh[BNODES], cur[BNODES], base_[BNODES];  // 1536 B
    __shared__ float4 w4[NREL * 2];                // 2880 B -> 52800 total (3 blk/CU)
    int tid = threadIdx.x, b = blockIdx.x;
    for (int i = tid; i < BNODES * 90 / 4; i += 512) hist8w[i] = 0u;
    for (int i = tid; i < NREL * 2; i += 512) {
        int r = i >> 1;
        w4[i] = (i & 1) ? make_float4(W[r * 6 + 4], W[r * 6 + 5], 0.f, 0.f)
                        : make_float4(W[r * 6], W[r * 6 + 1], W[r * 6 + 2], W[r * 6 + 3]);
    }
    __syncthreads();
    int e0 = bbase[b];
    int e1 = (b + 1 < NBINS) ? bbase[b + 1] : E;
    int cnt = e1 - e0;
    // phase A: ONE global read; records stay in VGPRs; u8 hist atomics
    unsigned rec[MAXK];
#pragma unroll
    for (int k = 0; k < MAXK; k++) {
        int idx = tid + k * 512;
        if (idx < cnt) {
            unsigned p = edges[e0 + idx];
            rec[k] = p;
            unsigned bi = (p >> 24) * 90u + ((p >> 17) & 127u);
            atomicAdd(&hist8w[bi >> 2], 1u << ((bi & 3) << 3));
        }
    }
    __syncthreads();
    if (tid < BNODES) {   // per-dst totals (byte sum over the dst's 90-byte row)
        const unsigned char* h8 = (const unsigned char*)hist8w;
        unsigned s = 0;
        for (int k = 0; k < 90; k++) s += h8[tid * 90 + k];
        hh[tid] = (int)s;
    }
    __syncthreads();
    if (tid < 64) {       // exclusive scan of 128 bins, 2/lane
        int c0 = hh[2 * tid], c1 = hh[2 * tid + 1];
        int s = c0 + c1;
        int inc = s;
#pragma unroll
        for (int off = 1; off < 64; off <<= 1) {
            int u = __shfl_up(inc, off);
            if (tid >= off) inc += u;
        }
        int run = inc - s;
        base_[2 * tid] = run;          cur[2 * tid] = run;
        base_[2 * tid + 1] = run + c0; cur[2 * tid + 1] = run + c0;
    }
    __syncthreads();
    if (tid < BNODES) {
        int d = (b << BSH) + tid;
        if (d <= N) rowptr[d] = e0 + base_[tid];
    }
    // phase B: place full records from VGPRs into dst-sorted LDS stage
#pragma unroll
    for (int k = 0; k < MAXK; k++) {
        int idx = tid + k * 512;
        if (idx < cnt) {
            int pos = atomicAdd(&cur[rec[k] >> 24], 1);
            if (pos < STAGE) stage32[pos] = rec[k];
        }
    }
    __syncthreads();
    // phase C (fused L1): 32 groups of 16 lanes, 4 dsts each; stage read from LDS
    int grp = tid >> 4, l16 = tid & 15;
#pragma unroll
    for (int rd = 0; rd < 4; rd++) {
        int dL = grp + rd * 32;
        int segb = base_[dL];
        int sege = segb + hh[dL];
        if (sege > cnt) sege = cnt;
        float a0 = 0, a1 = 0, a2 = 0, a3 = 0, a4 = 0, a5 = 0;
        for (int q = segb + l16; q < sege; q += 16) {
            unsigned p = stage32[q];
            unsigned rel = (p >> 17) & 127u;
            unsigned bi = dL * 90u + rel;
            unsigned c = (hist8w[bi >> 2] >> ((bi & 3) << 3)) & 0xFFu;
            edges2[e0 + q] = (p & 0x00FFFFFFu) | (c << 24);
            float r = __builtin_amdgcn_rcpf((float)c);
            float4 xv = x4[p & 0x1FFFFu];
            unsigned rel2 = rel * 2u;
            float4 wa = w4[rel2], wb = w4[rel2 + 1];
            float x0 = xv.x * r, x1 = xv.y * r, x2 = xv.z * r;
            a0 += x0 * wa.x; a1 += x0 * wa.y;
            a2 += x1 * wa.z; a3 += x1 * wa.w;
            a4 += x2 * wb.x; a5 += x2 * wb.y;
        }
#pragma unroll
        for (int off = 8; off > 0; off >>= 1) {
            a0 += __shfl_down(a0, off); a1 += __shfl_down(a1, off); a2 += __shfl_down(a2, off);
            a3 += __shfl_down(a3, off); a4 += __shfl_down(a4, off); a5 += __shfl_down(a5, off);
        }
        if (l16 == 0) {
            int d = (b << BSH) + dL;
            if (d < N) {
                float4 xv = x4[d];
                float o[6] = {a0, a1, a2, a3, a4, a5};
#pragma unroll
                for (int j = 0; j < 6; j++)
                    o[j] = frelu(o[j] + xv.x * root[j] + xv.y * root[6 + j] +
                                 xv.z * root[12 + j] + bias[j]);
                h1p[d * 2]     = make_float4(o[0], o[1], o[2], o[3]);
                h1p[d * 2 + 1] = make_float4(o[4], o[5], 0.0f, 0.0f);
            }
        }
    }
}

// ---------- L2: 16 lanes per dst, sum aggr, fused node ----------
__launch_bounds__(256)
__global__ void l2_g(const int* __restrict__ rowptr, const unsigned* __restrict__ sorted,
                     const float4* __restrict__ h1p, const float* __restrict__ W,
                     const float* __restrict__ root, const float* __restrict__ bias,
                     float4* __restrict__ h2p, int N) {
    __shared__ float4 w4[NREL * 2];
    for (int i = threadIdx.x; i < NREL * 2; i += 256) {
        int r = i >> 1;
        w4[i] = (i & 1) ? make_float4(W[r * 6 + 4], W[r * 6 + 5], 0.f, 0.f)
                        : make_float4(W[r * 6], W[r * 6 + 1], W[r * 6 + 2], W[r * 6 + 3]);
    }
    __syncthreads();
    int grp = threadIdx.x >> 4, l16 = threadIdx.x & 15;
    int d = blockIdx.x * LPD + grp;
    if (d >= N) return;
    int beg = rowptr[d], end = rowptr[d + 1];
    float a0 = 0, a1 = 0, a2 = 0;
    int i = beg + l16;
    for (; i + 48 < end; i += 64) {
        unsigned p[4];
        float4 ha[4], hb[4];
#pragma unroll
        for (int k = 0; k < 4; k++) p[k] = sorted[i + k * 16];
#pragma unroll
        for (int k = 0; k < 4; k++) {
            unsigned s = p[k] & 0x1FFFFu;
            ha[k] = h1p[2 * s]; hb[k] = h1p[2 * s + 1];
        }
#pragma unroll
        for (int k = 0; k < 4; k++) {
            unsigned rel2 = ((p[k] >> 17) & 127u) * 2u;
            float4 wa = w4[rel2], wb = w4[rel2 + 1];
            a0 += ha[k].x * wa.x + ha[k].y * wa.y;
            a1 += ha[k].z * wa.z + ha[k].w * wa.w;
            a2 += hb[k].x * wb.x + hb[k].y * wb.y;
        }
    }
    for (; i < end; i += 16) {
        unsigned p = sorted[i];
        unsigned s = p & 0x1FFFFu;
        float4 ha = h1p[2 * s], hb = h1p[2 * s + 1];
        unsigned rel2 = ((p >> 17) & 127u) * 2u;
        float4 wa = w4[rel2], wb = w4[rel2 + 1];
        a0 += ha.x * wa.x + ha.y * wa.y;
        a1 += ha.z * wa.z + ha.w * wa.w;
        a2 += hb.x * wb.x + hb.y * wb.y;
    }
#pragma unroll
    for (int off = 8; off > 0; off >>= 1) {
        a0 += __shfl_down(a0, off); a1 += __shfl_down(a1, off); a2 += __shfl_down(a2, off);
    }
    if (l16 == 0) {
        float4 ha = h1p[2 * d], hb = h1p[2 * d + 1];
        float hv[6] = {ha.x, ha.y, ha.z, ha.w, hb.x, hb.y};
        float o[3] = {a0, a1, a2};
#pragma unroll
        for (int j = 0; j < 3; j++) {
            float v = o[j] + bias[j];
#pragma unroll
            for (int k = 0; k < 6; k++) v += hv[k] * root[k * 3 + j];
            o[j] = frelu(v);
        }
        h2p[d] = make_float4(o[0], o[1], o[2], 0.0f);
    }
}

// ---------- L3: 16 lanes per dst, mean via packed cnt, fused node + pool ----------
__launch_bounds__(256)
__global__ void l3_g(const int* __restrict__ rowptr, const unsigned* __restrict__ sorted,
                     const float4* __restrict__ h2p, const float* __restrict__ W,
                     const float* __restrict__ root, const float* __restrict__ bias,
                     const int* __restrict__ batch, float* __restrict__ partials, int N) {
    __shared__ float4 w4[NREL * 2];
    __shared__ float redsm[LPD][8];
    for (int i = threadIdx.x; i < NREL * 2; i += 256) {
        int r = i >> 1;
        w4[i] = (i & 1) ? make_float4(W[r * 6 + 4], W[r * 6 + 5], 0.f, 0.f)
                        : make_float4(W[r * 6], W[r * 6 + 1], W[r * 6 + 2], W[r * 6 + 3]);
    }
    __syncthreads();
    int grp = threadIdx.x >> 4, l16 = threadIdx.x & 15;
    int d = blockIdx.x * LPD + grp;
    float a0 = 0, a1 = 0, a2 = 0, a3 = 0, a4 = 0, a5 = 0;
    if (d < N) {
        int beg = rowptr[d], end = rowptr[d + 1];
        int i = beg + l16;
        for (; i + 48 < end; i += 64) {
            unsigned p[4];
            float4 xv[4];
#pragma unroll
            for (int k = 0; k < 4; k++) p[k] = sorted[i + k * 16];
#pragma unroll
            for (int k = 0; k < 4; k++) xv[k] = h2p[p[k] & 0x1FFFFu];
#pragma unroll
            for (int k = 0; k < 4; k++) {
                float r = __builtin_amdgcn_rcpf((float)(p[k] >> 24));
                unsigned rel2 = ((p[k] >> 17) & 127u) * 2u;
                float4 wa = w4[rel2], wb = w4[rel2 + 1];
                float x0 = xv[k].x * r, x1 = xv[k].y * r, x2 = xv[k].z * r;
                a0 += x0 * wa.x; a1 += x0 * wa.y;
                a2 += x1 * wa.z; a3 += x1 * wa.w;
                a4 += x2 * wb.x; a5 += x2 * wb.y;
            }
        }
        for (; i < end; i += 16) {
            unsigned p = sorted[i];
            float r = __builtin_amdgcn_rcpf((float)(p >> 24));
            float4 xv = h2p[p & 0x1FFFFu];
            unsigned rel2 = ((p >> 17) & 127u) * 2u;
            float4 wa = w4[rel2], wb = w4[rel2 + 1];
            float x0 = xv.x * r, x1 = xv.y * r, x2 = xv.z * r;
            a0 += x0 * wa.x; a1 += x0 * wa.y;
            a2 += x1 * wa.z; a3 += x1 * wa.w;
            a4 += x2 * wb.x; a5 += x2 * wb.y;
        }
    }
#pragma unroll
    for (int off = 8; off > 0; off >>= 1) {
        a0 += __shfl_down(a0, off); a1 += __shfl_down(a1, off); a2 += __shfl_down(a2, off);
        a3 += __shfl_down(a3, off); a4 += __shfl_down(a4, off); a5 += __shfl_down(a5, off);
    }
    if (l16 == 0) {
        float v[7] = {0, 0, 0, 0, 0, 0, 0};
        if (d < N && batch[d] == 0) {
            float4 xv = h2p[d];
            float o[6] = {a0, a1, a2, a3, a4, a5};
#pragma unroll
            for (int j = 0; j < 6; j++)
                v[j] = frelu(o[j] + xv.x * root[j] + xv.y * root[6 + j] +
                             xv.z * root[12 + j] + bias[j]);
            v[6] = 1.0f;
        }
#pragma unroll
        for (int k = 0; k < 7; k++) redsm[grp][k] = v[k];
    }
    __syncthreads();
    if (threadIdx.x < 7) {
        float t = 0;
#pragma unroll
        for (int g = 0; g < LPD; g++) t += redsm[g][threadIdx.x];
        partials[(size_t)blockIdx.x * 8 + threadIdx.x] = t;
    }
}

// ---------- finalize ----------
__global__ void pool_finalize(const float* __restrict__ partials, int nb,
                              float* __restrict__ out) {
    float v[7] = {0, 0, 0, 0, 0, 0, 0};
    for (int b = threadIdx.x; b < nb; b += blockDim.x) {
#pragma unroll
        for (int k = 0; k < 7; k++) v[k] += partials[(size_t)b * 8 + k];
    }
#pragma unroll
    for (int off = 32; off > 0; off >>= 1) {
#pragma unroll
        for (int k = 0; k < 7; k++) v[k] += __shfl_down(v[k], off);
    }
    __shared__ float sm[16][8];
    int wv = threadIdx.x >> 6, lane = threadIdx.x & 63;
    if (lane == 0) {
#pragma unroll
        for (int k = 0; k < 7; k++) sm[wv][k] = v[k];
    }
    __syncthreads();
    if (threadIdx.x == 0) {
        float t[7] = {0, 0, 0, 0, 0, 0, 0};
        int nw = blockDim.x >> 6;
        for (int q = 0; q < nw; q++) {
#pragma unroll
            for (int k = 0; k < 7; k++) t[k] += sm[q][k];
        }
        float c = t[6] < 1.0f ? 1.0f : t[6];
        float p[6], m = -1e30f;
#pragma unroll
        for (int j = 0; j < 6; j++) { p[j] = t[j] / c; m = fmaxf(m, p[j]); }
        float s = 0.0f;
#pragma unroll
        for (int j = 0; j < 6; j++) s += expf(p[j] - m);
        float lse = m + logf(s);
#pragma unroll
        for (int j = 0; j < 6; j++) out[j] = p[j] - lse;
    }
}

extern "C" void kernel_launch(void* const* d_in, const int* in_sizes, int n_in,
                              void* d_out, int out_size, void* d_ws, size_t ws_size,
                              hipStream_t stream) {
    const float* x     = (const float*)d_in[0];
    const int*   ei    = (const int*)d_in[1];
    const int*   batch = (const int*)d_in[2];
    const int*   etype = (const int*)d_in[3];
    const float* W1    = (const float*)d_in[4];
    const float* root1 = (const float*)d_in[5];
    const float* b1    = (const float*)d_in[6];
    const float* W2    = (const float*)d_in[7];
    const float* root2 = (const float*)d_in[8];
    const float* b2    = (const float*)d_in[9];
    const float* W3    = (const float*)d_in[10];
    const float* root3 = (const float*)d_in[11];
    const float* b3    = (const float*)d_in[12];

    const int N = in_sizes[0] / 3;
    const int E = in_sizes[1] / 2;
    const int* src = ei;
    const int* dst = ei + E;
    const int gG = (E + GCH - 1) / GCH;   // chunks

    char* ws = (char*)d_ws;
    size_t off = 0;
    auto alloc = [&](size_t bytes) -> void* {
        void* p = ws + off;
        off += (bytes + 255) & ~(size_t)255;
        return p;
    };
    int*      bhist   = (int*)     alloc(NBINS * sizeof(int));       // zeroed
    size_t zero_bytes = off;
    int*      bbase   = (int*)     alloc((NBINS + 1) * sizeof(int));
    int*      chist   = (int*)     alloc((size_t)gG * NBINS * sizeof(int));   // 3.8 MB
    int*      gbase   = (int*)     alloc((size_t)gG * NBINS * sizeof(int));   // 3.8 MB
    unsigned* edges   = (unsigned*)alloc((size_t)E * sizeof(unsigned));       // 25.6 MB
    unsigned* edges2  = (unsigned*)alloc((size_t)E * sizeof(unsigned));       // 25.6 MB
    int*      rowptr  = (int*)     alloc((size_t)(N + 1) * sizeof(int));
    float4*   x4      = (float4*)  alloc((size_t)N * sizeof(float4));
    float4*   h1p     = (float4*)  alloc((size_t)N * 2 * sizeof(float4));
    float4*   h2p     = (float4*)  alloc((size_t)N * sizeof(float4));
    const int NBUCK = (N + BNODES - 1) >> BSH;                                // 782
    const int gL    = (N + LPD - 1) / LPD;                                    // 6250
    float*    partials = (float*)  alloc((size_t)gL * 8 * sizeof(float));
    // total ~67 MB

    hipMemsetAsync(d_ws, 0, zero_bytes, stream);

    const int gNp = (N + 511) / 512;

    padhist_k<<<gNp + gG, 512, 0, stream>>>(x, x4, N, gNp, dst, bhist, chist, E);
    colscan_k<<<NBINS, 64, 0, stream>>>(bhist, bbase, chist, gbase, gG);
    group_k<<<gG, 512, 0, stream>>>(src, dst, etype, chist, gbase, edges, E);
    sortb_l1_k<<<NBUCK, 512, 0, stream>>>(bbase, edges, edges2, rowptr,
                                          x4, W1, root1, b1, h1p, N, E);

    l2_g<<<gL, 256, 0, stream>>>(rowptr, edges2, h1p, W2, root2, b2, h2p, N);
    l3_g<<<gL, 256, 0, stream>>>(rowptr, edges2, h2p, W3, root3, b3, batch, partials, N);
    pool_finalize<<<1, 1024, 0, stream>>>(partials, gL, (float*)d_out);
}